// Round 5
// baseline (508.929 us; speedup 1.0000x reference)
//
#include <hip/hip_runtime.h>
#include <math.h>

// Softmax splatting (softsplat, soft mode), fp32. B=4, C=16, H=512, W=960.
//
// v6 = v5 (strip-dense gather, proven 479us) + two fixes aimed at the
// launch-serialization + dependent-load-chain gap identified in r4:
//   * per-batch bins/inT buffers (220MB; harness fill proves ~480MiB ws)
//     -> ONE prep dispatch + ONE splat dispatch, blockIdx.z = batch.
//   * splat inner loop explicitly software-pipelined: entry pairs with
//     next-pair prefetch, so the uniform entry->row load chain spans
//     iterations instead of serializing inside one.
// Lessons encoded from earlier rounds:
//   r0/r1: LDS atomic scatter = ~700us wall      -> no atomics in splat.
//   r2:    readlane scan <=4/64 useful lanes     -> lane-per-pixel strips.
//   r3:    pixel-sorted CSR fill = 64B-line amp  -> band-clustered bin runs.
// Fallback: original verified 877us pair if workspace too small.

#define BB 4
#define CC 16
#define HH 512
#define WW 960
#define HWP (HH * WW)
#define EPSF 1e-7f

// ---------------- v6 constants ----------------
#define NSX 30                        // col strips (32 wide)
#define NSY 256                       // row strips (2 tall)
#define SPB (NSX * NSY)               // 7680 strips per batch
#define CAPS 192                      // mean ~99, 9-sigma headroom

// workspace: counts[BB][SPB] | bins[BB][SPB][CAPS] | inT[BB][HWP][16]
#define WS_BINS_OFF ((size_t)131072)
#define WS_INT_OFF  (WS_BINS_OFF + (size_t)BB * SPB * CAPS * 16) // 94,502,912
#define WS_NEED6    (WS_INT_OFF + (size_t)BB * HWP * 64)         // 220,332,032

// ---------------- fallback constants ----------------
#define TSX 32
#define TSY 16
#define TNX (WW / TSX)
#define TNY (HH / TSY)
#define TPB (TNX * TNY)
#define NTILE (BB * TPB)
#define CAP 1536

// ================= v6 path =================

__launch_bounds__(256)
__global__ void prep6(const float* __restrict__ in,
                      const float* __restrict__ flow,
                      const float* __restrict__ metric,
                      unsigned int* __restrict__ counts,   // [BB][SPB]
                      uint4* __restrict__ bins,            // [BB][SPB][CAPS]
                      float4* __restrict__ inT)            // [BB][HWP][4]
{
    __shared__ unsigned int lcnt[SPB];   // 30720 B

    int b = blockIdx.z;
    int x = blockIdx.x * 32 + (threadIdx.x & 31);
    int y = blockIdx.y * 8  + (threadIdx.x >> 5);
    int p = y * WW + x;

    unsigned int* cb = counts + (size_t)b * SPB;
    uint4*        bb = bins   + (size_t)b * SPB * CAPS;

    for (int i = threadIdx.x; i < SPB; i += 256) lcnt[i] = 0;
    __syncthreads();

    float dx = flow[(size_t)(b * 2 + 0) * HWP + p];
    float dy = flow[(size_t)(b * 2 + 1) * HWP + p];
    float m  = expf(metric[(size_t)b * HWP + p]);

    // channels-last transpose (plain values; m rides in entry weights)
    const float* ib = in + (size_t)b * CC * HWP + p;
    float4* o = inT + ((size_t)b * HWP + p) * 4;
#pragma unroll
    for (int k = 0; k < 4; ++k) {
        float4 r;
        r.x = ib[(size_t)(4 * k + 0) * HWP];
        r.y = ib[(size_t)(4 * k + 1) * HWP];
        r.z = ib[(size_t)(4 * k + 2) * HWP];
        r.w = ib[(size_t)(4 * k + 3) * HWP];
        o[k] = r;
    }

    float fx = (float)x + dx, fy = (float)y + dy;
    float x0f = floorf(fx),   y0f = floorf(fy);
    int   x0 = (int)x0f,      y0 = (int)y0f;
    float wx1 = fx - x0f,     wy1 = fy - y0f;
    float wy0m = (1.0f - wy1) * m, wy1m = wy1 * m;

    int sxA = x0 >> 5, sxB = (x0 + 1) >> 5;     // arithmetic shift: floor div
    int syA = y0 >> 1, syB = (y0 + 1) >> 1;
    bool dupX = (sxB != sxA);
    bool dupY = (syB != syA);                   // == (y0 odd, incl. negatives)

    // strip syA holds rows {2syA, 2syA+1}; strip syB holds row y0+1 only
    float w0AB = dupY ? 0.0f  : wy0m;
    float w1AB = dupY ? wy0m  : wy1m;
    float w0CD = wy1m;                          // only used when dupY

    bool vA = (sxA >= 0 && sxA < NSX && syA >= 0 && syA < NSY);
    bool vB = dupX && (sxB >= 0 && sxB < NSX && syA >= 0 && syA < NSY);
    bool vC = dupY && (sxA >= 0 && sxA < NSX && syB >= 0 && syB < NSY);
    bool vD = dupX && dupY && (sxB >= 0 && sxB < NSX && syB >= 0 && syB < NSY);

    int tA = syA * NSX + sxA, tB = syA * NSX + sxB;
    int tC = syB * NSX + sxA, tD = syB * NSX + sxB;

    unsigned int rA = 0, rB = 0, rC = 0, rD = 0;
    if (vA) rA = atomicAdd(&lcnt[tA], 1u);
    if (vB) rB = atomicAdd(&lcnt[tB], 1u);
    if (vC) rC = atomicAdd(&lcnt[tC], 1u);
    if (vD) rD = atomicAdd(&lcnt[tD], 1u);

    __syncthreads();

    // one contiguous global run per nonempty strip; base replaces count
    for (int i = threadIdx.x; i < SPB; i += 256) {
        unsigned int c = lcnt[i];
        if (c) lcnt[i] = atomicAdd(&cb[i], c);
    }
    __syncthreads();

    unsigned int pkA = (unsigned int)p | ((unsigned int)((x0 - (sxA << 5)) + 1) << 19);
    unsigned int pkB = (unsigned int)p;         // cx = -1 -> (cx+1) = 0
    unsigned int uwx = __float_as_uint(wx1);

    if (vA) { unsigned int pos = lcnt[tA] + rA;
        if (pos < CAPS) bb[(size_t)tA * CAPS + pos] =
            make_uint4(pkA, uwx, __float_as_uint(w0AB), __float_as_uint(w1AB)); }
    if (vB) { unsigned int pos = lcnt[tB] + rB;
        if (pos < CAPS) bb[(size_t)tB * CAPS + pos] =
            make_uint4(pkB, uwx, __float_as_uint(w0AB), __float_as_uint(w1AB)); }
    if (vC) { unsigned int pos = lcnt[tC] + rC;
        if (pos < CAPS) bb[(size_t)tC * CAPS + pos] =
            make_uint4(pkA, uwx, __float_as_uint(w0CD), __float_as_uint(0.0f)); }
    if (vD) { unsigned int pos = lcnt[tD] + rD;
        if (pos < CAPS) bb[(size_t)tD * CAPS + pos] =
            make_uint4(pkB, uwx, __float_as_uint(w0CD), __float_as_uint(0.0f)); }
}

__launch_bounds__(256)
__global__ void splat6(const float4* __restrict__ inT,
                       const unsigned int* __restrict__ counts,
                       const uint4* __restrict__ bins,
                       float* __restrict__ out)
{
    int wave = threadIdx.x >> 6;
    int lane = threadIdx.x & 63;
    int b    = blockIdx.z;
    int bx   = blockIdx.x;               // 0..29
    int sy   = blockIdx.y * 4 + wave;    // 0..255
    // wave-uniform chain -> scalar-path loads for count/entry/row
    int s = __builtin_amdgcn_readfirstlane(sy * NSX + bx);

    unsigned int n = counts[(size_t)b * SPB + s];
    if (n > CAPS) n = CAPS;
    const uint4*  bs  = bins + ((size_t)b * SPB + s) * CAPS;
    const float4* ibT = inT + (size_t)b * HWP * 4;

    int lx = lane & 31;                  // owned col within strip
    int ly = lane >> 5;                  // owned row within strip (0/1)

    float4 A = make_float4(0.f,0.f,0.f,0.f), B = A, C = A, D = A;
    float  aw = 0.f;

    // zero-padded guarded load: an all-zero entry contributes w==0 exactly
    // (e.y = e.z = e.w = 0) and gathers row p=0 (valid memory).
    #define LOADE(idx) (((unsigned int)(idx) < n) ? bs[idx] \
                                                  : make_uint4(0u,0u,0u,0u))

    #define DOFMA(eK, t0, t1, t2, t3)                                          \
        {                                                                      \
            int   cx  = (int)((eK.x >> 19) & 63u) - 1;                         \
            float wx1 = __uint_as_float(eK.y);                                 \
            float wrm = __uint_as_float(ly ? eK.w : eK.z);                     \
            float wx  = (lx == cx) ? (1.0f - wx1)                              \
                      : ((lx == cx + 1) ? wx1 : 0.0f);                         \
            float w   = wx * wrm;                                              \
            A.x += w*t0.x; A.y += w*t0.y; A.z += w*t0.z; A.w += w*t0.w;        \
            B.x += w*t1.x; B.y += w*t1.y; B.z += w*t1.z; B.w += w*t1.w;        \
            C.x += w*t2.x; C.y += w*t2.y; C.z += w*t2.z; C.w += w*t2.w;        \
            D.x += w*t3.x; D.y += w*t3.y; D.z += w*t3.z; D.w += w*t3.w;        \
            aw  += w;                                                          \
        }

    // software pipeline: entries for iteration j+2 prefetched during j, so
    // the entry->row dependency never serializes within one iteration.
    uint4 e0 = LOADE(0), e1 = LOADE(1);
    for (unsigned int j = 0; j < n; j += 2) {
        // rows for current pair (addresses ready: entries arrived last iter)
        const float4* r0 = ibT + (size_t)(e0.x & 0x7FFFFu) * 4;
        const float4* r1 = ibT + (size_t)(e1.x & 0x7FFFFu) * 4;
        float4 t00 = r0[0], t01 = r0[1], t02 = r0[2], t03 = r0[3];
        float4 t10 = r1[0], t11 = r1[1], t12 = r1[2], t13 = r1[3];
        // prefetch next pair (overlaps with row latency + FMA below)
        uint4 f0 = LOADE(j + 2), f1 = LOADE(j + 3);
        DOFMA(e0, t00, t01, t02, t03)
        DOFMA(e1, t10, t11, t12, t13)
        e0 = f0; e1 = f1;
    }
    #undef DOFMA
    #undef LOADE

    // coalesced writeback + fused normalization: one pixel per lane
    float inv = 1.0f / (aw + EPSF);
    int xg = bx * 32 + lx;
    int yg = sy * 2 + ly;
    float* ob = out + (size_t)b * CC * HWP + (size_t)yg * WW + xg;
    ob[(size_t) 0 * HWP] = A.x * inv;  ob[(size_t) 1 * HWP] = A.y * inv;
    ob[(size_t) 2 * HWP] = A.z * inv;  ob[(size_t) 3 * HWP] = A.w * inv;
    ob[(size_t) 4 * HWP] = B.x * inv;  ob[(size_t) 5 * HWP] = B.y * inv;
    ob[(size_t) 6 * HWP] = B.z * inv;  ob[(size_t) 7 * HWP] = B.w * inv;
    ob[(size_t) 8 * HWP] = C.x * inv;  ob[(size_t) 9 * HWP] = C.y * inv;
    ob[(size_t)10 * HWP] = C.z * inv;  ob[(size_t)11 * HWP] = C.w * inv;
    ob[(size_t)12 * HWP] = D.x * inv;  ob[(size_t)13 * HWP] = D.y * inv;
    ob[(size_t)14 * HWP] = D.z * inv;  ob[(size_t)15 * HWP] = D.w * inv;
}

// ================= fallback (original verified 877us) path =================

__launch_bounds__(256)
__global__ void bin_kernel(const float* __restrict__ flow,
                           unsigned int* __restrict__ counts,
                           unsigned int* __restrict__ bins)
{
    __shared__ unsigned int lcnt[TPB];

    int b  = blockIdx.z;
    int x  = blockIdx.x * 32 + (threadIdx.x & 31);
    int y  = blockIdx.y * 8  + (threadIdx.x >> 5);
    int p  = y * WW + x;

    for (int i = threadIdx.x; i < TPB; i += 256) lcnt[i] = 0;
    __syncthreads();

    float dx = flow[(size_t)(b * 2 + 0) * HWP + p];
    float dy = flow[(size_t)(b * 2 + 1) * HWP + p];
    int x0 = (int)floorf((float)x + dx);
    int y0 = (int)floorf((float)y + dy);

    int txA = x0 >> 5, txB = (x0 + 1) >> 5;
    int tyA = y0 >> 4, tyB = (y0 + 1) >> 4;

    int          tA[4];
    unsigned int rA[4];
    int cnt = 0;

    #define TRYINS(tx_, ty_)                                                   \
        if ((tx_) >= 0 && (tx_) < TNX && (ty_) >= 0 && (ty_) < TNY) {          \
            int t_ = (ty_) * TNX + (tx_);                                      \
            rA[cnt] = atomicAdd(&lcnt[t_], 1u);                                \
            tA[cnt] = t_;                                                      \
            ++cnt;                                                             \
        }

    TRYINS(txA, tyA);
    if (txB != txA) TRYINS(txB, tyA);
    if (tyB != tyA) {
        TRYINS(txA, tyB);
        if (txB != txA) TRYINS(txB, tyB);
    }
    #undef TRYINS

    __syncthreads();

    for (int i = threadIdx.x; i < TPB; i += 256) {
        unsigned int c = lcnt[i];
        if (c) lcnt[i] = atomicAdd(&counts[b * TPB + i], c);
    }
    __syncthreads();

    unsigned int e = ((unsigned int)y << 10) | (unsigned int)x;
    for (int k = 0; k < cnt; ++k) {
        int t_ = tA[k];
        unsigned int pos = lcnt[t_] + rA[k];
        if (pos < CAP)
            bins[((size_t)(b * TPB) + t_) * CAP + pos] = e;
    }
}

__launch_bounds__(256)
__global__ void tile_kernel(const float* __restrict__ in,
                            const float* __restrict__ flow,
                            const float* __restrict__ metric,
                            const unsigned int* __restrict__ counts,
                            const unsigned int* __restrict__ bins,
                            float* __restrict__ out)
{
    __shared__ float acc[TSX * TSY * 17];

    int tile = blockIdx.x;
    int b  = tile / TPB;
    int t  = tile - b * TPB;
    int ty = t / TNX;
    int tx = t - ty * TNX;
    int tid = threadIdx.x;

    for (int i = tid; i < TSX * TSY * 17; i += 256) acc[i] = 0.0f;
    __syncthreads();

    unsigned int n = counts[tile];
    if (n > CAP) n = CAP;

    for (unsigned int base = 0; base < n; base += 256) {
        unsigned int i = base + tid;
        if (i < n) {
            unsigned int e = bins[(size_t)tile * CAP + i];
            int x = (int)(e & 1023u);
            int y = (int)(e >> 10);
            int p = y * WW + x;

            float dx = flow[(size_t)(b * 2 + 0) * HWP + p];
            float dy = flow[(size_t)(b * 2 + 1) * HWP + p];
            float m  = expf(metric[(size_t)b * HWP + p]);

            float fx = (float)x + dx;
            float fy = (float)y + dy;
            float x0f = floorf(fx), y0f = floorf(fy);
            int   x0  = (int)x0f,   y0  = (int)y0f;
            float wx1 = fx - x0f,   wy1 = fy - y0f;
            float wx0 = 1.0f - wx1, wy0 = 1.0f - wy1;

            float v[CC];
            const float* inp = in + (size_t)b * CC * HWP + p;
#pragma unroll
            for (int c = 0; c < CC; ++c) v[c] = inp[(size_t)c * HWP] * m;

            const int   xs[4] = { x0,        x0 + 1,    x0,        x0 + 1    };
            const int   ys[4] = { y0,        y0,        y0 + 1,    y0 + 1    };
            const float ws[4] = { wx0 * wy0, wx1 * wy0, wx0 * wy1, wx1 * wy1 };

#pragma unroll
            for (int k = 0; k < 4; ++k) {
                int xi = xs[k], yi = ys[k];
                if ((xi >> 5) == tx && (yi >> 4) == ty) {
                    float wgt = ws[k];
                    int q = ((yi & 15) * TSX + (xi & 31)) * 17;
#pragma unroll
                    for (int c = 0; c < CC; ++c)
                        atomicAdd(&acc[q + c], v[c] * wgt);
                    atomicAdd(&acc[q + CC], m * wgt);
                }
            }
        }
    }
    __syncthreads();

    for (int q = tid; q < TSX * TSY; q += 256) {
        int ly = q >> 5, lx = q & 31;
        int gp = (ty * TSY + ly) * WW + tx * TSX + lx;
        float inv = 1.0f / (acc[q * 17 + CC] + EPSF);
        float* op = out + (size_t)b * CC * HWP + gp;
#pragma unroll
        for (int c = 0; c < CC; ++c)
            op[(size_t)c * HWP] = acc[q * 17 + c] * inv;
    }
}

// ================= launch =================

extern "C" void kernel_launch(void* const* d_in, const int* in_sizes, int n_in,
                              void* d_out, int out_size, void* d_ws, size_t ws_size,
                              hipStream_t stream) {
    const float* in     = (const float*)d_in[0];
    const float* flow   = (const float*)d_in[1];
    const float* metric = (const float*)d_in[2];
    float* out = (float*)d_out;

    if (ws_size >= WS_NEED6) {
        unsigned int* counts = (unsigned int*)d_ws;      // [BB][SPB]
        uint4*        bins   = (uint4*)((char*)d_ws + WS_BINS_OFF);
        float4*       inT    = (float4*)((char*)d_ws + WS_INT_OFF);

        hipMemsetAsync(counts, 0, (size_t)BB * SPB * 4, stream);

        prep6 <<<dim3(NSX, 64, BB), dim3(256), 0, stream>>>(
            in, flow, metric, counts, bins, inT);
        splat6<<<dim3(NSX, 64, BB), dim3(256), 0, stream>>>(
            inT, counts, bins, out);
    } else {
        // fallback: original verified path (~877 us)
        unsigned int* counts = (unsigned int*)d_ws;
        unsigned int* bins   = (unsigned int*)((char*)d_ws + 16384);

        hipMemsetAsync(counts, 0, NTILE * sizeof(unsigned int), stream);

        bin_kernel<<<dim3(WW / 32, HH / 8, BB), dim3(256), 0, stream>>>(flow, counts, bins);
        tile_kernel<<<dim3(NTILE), dim3(256), 0, stream>>>(in, flow, metric, counts, bins, out);
    }
}